// Round 4
// baseline (11100.326 us; speedup 1.0000x reference)
//
#include <hip/hip_runtime.h>
#include <math.h>

#define LATENT 256
#define HIDDEN 512
#define MAXN   64
#define BATCH  128
#define NPAIR  2016   // 64*63/2
#define G3     1536   // 3*HIDDEN

// ---------------------------------------------------------------------------
// ZC kernel: rows 0..127 -> Z[b,o] = z[b,:]@W_pre[o,:256]
//            rows 128..191 -> C[m,o] = pe[m,:]@W_pre[o,:256] + emb[m,:]@W_pre[o,256:512] + b_pre[o]
// ---------------------------------------------------------------------------
__global__ __launch_bounds__(256) void zc_kernel(
    const float* __restrict__ z, const float* __restrict__ pe,
    const float* __restrict__ emb, const float* __restrict__ W_pre,
    const float* __restrict__ b_pre, float* __restrict__ ZC)
{
  __shared__ float s1[256];
  __shared__ float s2[256];
  int row = blockIdx.x;     // 0..191
  int o = threadIdx.x;      // 0..255
  const float* wr = W_pre + (size_t)o * 512;
  if (row < 128) {
    s1[o] = z[row * 256 + o];
    __syncthreads();
    float acc = 0.f;
    #pragma unroll 8
    for (int k = 0; k < 256; k += 4) {
      float4 w4 = *(const float4*)(wr + k);
      float4 x4 = *(const float4*)(&s1[k]);
      acc += x4.x * w4.x; acc += x4.y * w4.y; acc += x4.z * w4.z; acc += x4.w * w4.w;
    }
    ZC[row * 256 + o] = acc;
  } else {
    int m = row - 128;
    s1[o] = pe[m * 256 + o];
    s2[o] = emb[m * 256 + o];
    __syncthreads();
    float acc = b_pre[o];
    #pragma unroll 8
    for (int k = 0; k < 256; k += 4) {
      float4 w4 = *(const float4*)(wr + k);
      float4 x4 = *(const float4*)(&s1[k]);
      acc += x4.x * w4.x; acc += x4.y * w4.y; acc += x4.z * w4.z; acc += x4.w * w4.w;
    }
    #pragma unroll 8
    for (int k = 0; k < 256; k += 4) {
      float4 w4 = *(const float4*)(wr + 256 + k);
      float4 x4 = *(const float4*)(&s2[k]);
      acc += x4.x * w4.x; acc += x4.y * w4.y; acc += x4.z * w4.z; acc += x4.w * w4.w;
    }
    ZC[row * 256 + o] = acc;
  }
}

// ---------------------------------------------------------------------------
// Generic f32 GEMM: C[M,N] = A[M,K] @ W[N,K]^T (+bias), optional per-row mask.
// Tiles: 128x128x16, 256 threads, 8x8 micro-tile (split 4+4 to avoid stride-8
// LDS conflicts; pad 137).
// MASK: row m -> t=m>>7, b=m&127 (H layout [t][b]), zero if t >= n_nodes[b].
// ---------------------------------------------------------------------------
template<bool MASK>
__global__ __launch_bounds__(256) void gemm_kernel(
    const float* __restrict__ A, int lda,
    const float* __restrict__ W, int ldw,
    const float* __restrict__ bias,
    float* __restrict__ C, int ldc,
    int M, int N, int K,
    const int* __restrict__ n_nodes)
{
  __shared__ float As[16][137];
  __shared__ float Ws[16][137];
  const int tid = threadIdx.x;
  const int tx = tid & 15, ty = tid >> 4;
  const int row0 = blockIdx.y * 128, col0 = blockIdx.x * 128;

  float acc[8][8];
  #pragma unroll
  for (int i = 0; i < 8; i++)
    #pragma unroll
    for (int j = 0; j < 8; j++) acc[i][j] = 0.f;

  for (int k0 = 0; k0 < K; k0 += 16) {
    #pragma unroll
    for (int s = 0; s < 2; s++) {
      int q = tid + 256 * s;
      int r = q >> 2;
      int c4 = (q & 3) << 2;
      int gm = row0 + r;
      float4 v = make_float4(0.f, 0.f, 0.f, 0.f);
      if (gm < M) {
        v = *(const float4*)(A + (size_t)gm * lda + k0 + c4);
        if (MASK) {
          int tt = gm >> 7, bb = gm & 127;
          if (tt >= n_nodes[bb]) v = make_float4(0.f, 0.f, 0.f, 0.f);
        }
      }
      As[c4 + 0][r] = v.x; As[c4 + 1][r] = v.y; As[c4 + 2][r] = v.z; As[c4 + 3][r] = v.w;
      int gn = col0 + r;
      float4 w = *(const float4*)(W + (size_t)gn * ldw + k0 + c4);
      Ws[c4 + 0][r] = w.x; Ws[c4 + 1][r] = w.y; Ws[c4 + 2][r] = w.z; Ws[c4 + 3][r] = w.w;
    }
    __syncthreads();
    #pragma unroll
    for (int kk = 0; kk < 16; kk++) {
      float4 a0 = *(const float4*)&As[kk][ty * 4];
      float4 a1 = *(const float4*)&As[kk][64 + ty * 4];
      float4 b0 = *(const float4*)&Ws[kk][tx * 4];
      float4 b1 = *(const float4*)&Ws[kk][64 + tx * 4];
      float av[8] = {a0.x, a0.y, a0.z, a0.w, a1.x, a1.y, a1.z, a1.w};
      float bv[8] = {b0.x, b0.y, b0.z, b0.w, b1.x, b1.y, b1.z, b1.w};
      #pragma unroll
      for (int i = 0; i < 8; i++)
        #pragma unroll
        for (int j = 0; j < 8; j++)
          acc[i][j] += av[i] * bv[j];
    }
    __syncthreads();
  }

  float bb[8];
  #pragma unroll
  for (int j = 0; j < 8; j++) {
    int gc = col0 + (j < 4 ? tx * 4 + j : 64 + tx * 4 + j - 4);
    bb[j] = bias ? bias[gc] : 0.f;
  }
  #pragma unroll
  for (int i = 0; i < 8; i++) {
    int gm = row0 + (i < 4 ? ty * 4 + i : 64 + ty * 4 + i - 4);
    if (gm < M) {
      float* out = C + (size_t)gm * ldc + col0;
      float4 o0 = make_float4(acc[i][0] + bb[0], acc[i][1] + bb[1], acc[i][2] + bb[2], acc[i][3] + bb[3]);
      float4 o1 = make_float4(acc[i][4] + bb[4], acc[i][5] + bb[5], acc[i][6] + bb[6], acc[i][7] + bb[7]);
      *(float4*)(out + tx * 4) = o0;
      *(float4*)(out + 64 + tx * 4) = o1;
    }
  }
}

// ---------------------------------------------------------------------------
// WAB precompute: WAB[o,k] (1024x512)
// ---------------------------------------------------------------------------
__global__ __launch_bounds__(256) void wab_kernel(
    const float* __restrict__ adj_W1, const float* __restrict__ node_W,
    float* __restrict__ WAB)
{
  int k = blockIdx.x * 256 + threadIdx.x;  // 0..511
  int o0 = blockIdx.y * 8;
  int sel = blockIdx.z;
  const float* a1 = adj_W1 + (sel ? 512 : 0);
  float acc[8] = {0.f, 0.f, 0.f, 0.f, 0.f, 0.f, 0.f, 0.f};
  for (int j = 0; j < 512; j++) {
    float w = node_W[(size_t)j * 512 + k];
    #pragma unroll
    for (int oo = 0; oo < 8; oo++)
      acc[oo] += a1[(size_t)(o0 + oo) * 1024 + j] * w;
  }
  #pragma unroll
  for (int oo = 0; oo < 8; oo++)
    WAB[(size_t)(sel * 512 + o0 + oo) * 512 + k] = acc[oo];
}

// ---------------------------------------------------------------------------
// Persistent cooperative GRU layer, v2: Whh in REGISTERS.
// Grid 256 x 512. group gg = blockIdx&15 (8 batches, b0=gg*8).
// o-slice r = blockIdx>>4 (32 rows, o0=r*32). Thread (ol=tid&31, kq=tid>>5)
// holds Whh[o0+ol][kq*32..+32) x 3 gates in 96 VGPRs for the whole kernel.
// __launch_bounds__(512, 2): 2 waves/EU -> 256-VGPR cap. Round 3 lesson:
// the default cap (128) spilled the weight arrays to scratch -> 8.8 GB/dispatch
// HBM fetch and 25x slowdown. ~170 VGPRs needed; DO NOT tighten this bound.
// Barrier: RELAXED spin + single ACQUIRE; RELEASE add. One L2 inv/step.
// MODE 0: gi = mask*(Z[b]+C[t]) + bih0 from ZCW; MODE 1: gi = GI1[t*128+b].
// ---------------------------------------------------------------------------
template<int MODE>
__global__ __launch_bounds__(512, 2) void coop_gru_kernel(
    const float* __restrict__ Whh, const float* __restrict__ bhh,
    float* __restrict__ Hbuf, const float* __restrict__ gi,
    const float* __restrict__ bih, const int* __restrict__ n_nodes,
    unsigned int* cnts)
{
  __shared__ float h_s[8 * 512];          // 16 KB: h(t-1) for our 8 batches
  __shared__ float scr[8 * 3 * 8 * 32];   // 24 KB: wave x gate x batch x ol
  __shared__ float zb[3 * 8 * 32];        // MODE0 Z part (t-invariant)
  __shared__ float bhh_s[96];
  __shared__ float bih_s[96];
  __shared__ int   nn_s[8];

  const int tid = threadIdx.x;
  const int ol = tid & 31, kq = tid >> 5;       // kq 0..15
  const int gg = blockIdx.x & 15, r = blockIdx.x >> 4;
  const int b0 = gg * 8, o0 = r * 32;
  unsigned int* cnt = cnts + gg * 64;           // 256B-spaced counters

  // one-time preloads
  if (tid < 96) bhh_s[tid] = bhh[(tid >> 5) * 512 + o0 + (tid & 31)];
  if (MODE == 0) {
    if (tid < 96) bih_s[tid] = bih[(tid >> 5) * 512 + o0 + (tid & 31)];
    if (tid < 8) nn_s[tid] = n_nodes[b0 + tid];
    #pragma unroll
    for (int s = 0; s < 2; s++) {
      int q = tid + 512 * s;
      if (q < 768) {
        int g = q >> 8, b = (q >> 5) & 7, o = q & 31;
        zb[q] = gi[(size_t)(b0 + b) * G3 + g * 512 + o0 + o];
      }
    }
  }

  // weights -> registers (held across all 64 steps)
  const float* wb = Whh + (size_t)(o0 + ol) * 512 + kq * 32;
  float4 wr_[8], wz_[8], wn_[8];
  #pragma unroll
  for (int j = 0; j < 8; j++) {
    wr_[j] = *(const float4*)(wb + j * 4);
    wz_[j] = *(const float4*)(wb + 262144 + j * 4);
    wn_[j] = *(const float4*)(wb + 524288 + j * 4);
  }
  __syncthreads();

  const int lane = tid & 63, wl = tid >> 6;

  for (int t = 0; t < 64; t++) {
    if (t > 0) {
      #pragma unroll
      for (int s = 0; s < 2; s++) {
        int q = tid + 512 * s;
        int rb = q >> 7, c = (q & 127) << 2;
        *(float4*)&h_s[rb * 512 + c] =
            *(const float4*)(Hbuf + ((size_t)((t - 1) * 128 + b0 + rb)) * 512 + c);
      }
    }
    __syncthreads();

    float accr[8], accz[8], accn[8];
    #pragma unroll
    for (int b = 0; b < 8; b++) { accr[b] = 0.f; accz[b] = 0.f; accn[b] = 0.f; }

    if (t > 0) {
      #pragma unroll
      for (int b = 0; b < 8; b++) {
        const float* hb = &h_s[b * 512 + kq * 32];
        #pragma unroll
        for (int j = 0; j < 8; j++) {
          float4 h4 = *(const float4*)(hb + j * 4);
          accr[b] += h4.x * wr_[j].x + h4.y * wr_[j].y + h4.z * wr_[j].z + h4.w * wr_[j].w;
          accz[b] += h4.x * wz_[j].x + h4.y * wz_[j].y + h4.z * wz_[j].z + h4.w * wz_[j].w;
          accn[b] += h4.x * wn_[j].x + h4.y * wn_[j].y + h4.z * wn_[j].z + h4.w * wn_[j].w;
        }
      }
      // reduce kq pair within wave (lanes 0..31 <-> 32..63 share ol)
      #pragma unroll
      for (int b = 0; b < 8; b++) {
        accr[b] += __shfl_xor(accr[b], 32, 64);
        accz[b] += __shfl_xor(accz[b], 32, 64);
        accn[b] += __shfl_xor(accn[b], 32, 64);
      }
    }

    if (lane < 32) {
      #pragma unroll
      for (int b = 0; b < 8; b++) {
        scr[((wl * 3 + 0) * 8 + b) * 32 + ol] = accr[b];
        scr[((wl * 3 + 1) * 8 + b) * 32 + ol] = accz[b];
        scr[((wl * 3 + 2) * 8 + b) * 32 + ol] = accn[b];
      }
    }
    __syncthreads();

    if (tid < 256) {
      int b = tid >> 5, o = tid & 31;
      float sr = 0.f, sz = 0.f, sn = 0.f;
      #pragma unroll
      for (int w = 0; w < 8; w++) {
        sr += scr[((w * 3 + 0) * 8 + b) * 32 + o];
        sz += scr[((w * 3 + 1) * 8 + b) * 32 + o];
        sn += scr[((w * 3 + 2) * 8 + b) * 32 + o];
      }
      float hr = sr + bhh_s[o];
      float hz = sz + bhh_s[32 + o];
      float hn = sn + bhh_s[64 + o];
      float ir, iz, inn;
      if (MODE == 0) {
        bool mk = (t < nn_s[b]);
        const float* ct = gi + (size_t)(128 + t) * G3 + o0 + o;
        float vr = zb[(0 * 8 + b) * 32 + o] + ct[0];
        float vz = zb[(1 * 8 + b) * 32 + o] + ct[512];
        float vn = zb[(2 * 8 + b) * 32 + o] + ct[1024];
        ir  = (mk ? vr : 0.f) + bih_s[o];
        iz  = (mk ? vz : 0.f) + bih_s[32 + o];
        inn = (mk ? vn : 0.f) + bih_s[64 + o];
      } else {
        const float* g1 = gi + (size_t)(t * 128 + b0 + b) * G3 + o0 + o;
        ir = g1[0]; iz = g1[512]; inn = g1[1024];
      }
      float rg = 1.f / (1.f + expf(-(ir + hr)));
      float zg = 1.f / (1.f + expf(-(iz + hz)));
      float ng = tanhf(inn + rg * hn);
      float hp = (t > 0) ? h_s[b * 512 + o0 + o] : 0.f;
      float hnew = (1.f - zg) * ng + zg * hp;
      Hbuf[((size_t)(t * 128 + b0 + b)) * 512 + o0 + o] = hnew;
    }

    if (t < 63) {
      __syncthreads();   // all stores of this block done
      if (tid == 0) {
        __hip_atomic_fetch_add(cnt, 1u, __ATOMIC_RELEASE, __HIP_MEMORY_SCOPE_AGENT);
        unsigned target = 16u * (unsigned)(t + 1);
        while (__hip_atomic_load(cnt, __ATOMIC_RELAXED, __HIP_MEMORY_SCOPE_AGENT) < target)
          __builtin_amdgcn_s_sleep(2);
        (void)__hip_atomic_load(cnt, __ATOMIC_ACQUIRE, __HIP_MEMORY_SCOPE_AGENT);
      }
      __syncthreads();
    }
  }
}

// ---------------------------------------------------------------------------
// Diagonal zero
// ---------------------------------------------------------------------------
__global__ void diag_kernel(float* __restrict__ adj)
{
  int x = blockIdx.x * 256 + threadIdx.x;
  if (x < 8192) {
    int b = x >> 6, d = x & 63;
    adj[(size_t)b * 4096 + d * 65] = 0.f;
  }
}

// ---------------------------------------------------------------------------
// Pair kernel: one wave per (b, pair). AB rows are [t*128+b] layout.
// ---------------------------------------------------------------------------
__global__ __launch_bounds__(256) void pair_kernel(
    const float* __restrict__ AB, const float* __restrict__ b1,
    const float* __restrict__ W2, const float* __restrict__ b2,
    const float* __restrict__ gu, const int* __restrict__ n_nodes,
    float* __restrict__ adj)
{
  int wid = blockIdx.x * 4 + (threadIdx.x >> 6);
  int lane = threadIdx.x & 63;
  int b = wid / NPAIR;
  int p = wid - b * NPAIR;

  float fp = (float)p;
  int i = (int)((127.0f - sqrtf(16129.0f - 8.0f * fp)) * 0.5f);
  if (i < 0) i = 0;
  if (i > 62) i = 62;
  while (i < 62 && (i + 1) * (126 - i) / 2 <= p) i++;
  while (i > 0 && i * (127 - i) / 2 > p) i--;
  int j = p - i * (127 - i) / 2 + i + 1;

  const float* arow = AB + ((size_t)(i * 128 + b)) * 1024;
  const float* brow = AB + ((size_t)(j * 128 + b)) * 1024 + 512;
  int k0 = lane * 8;

  float4 a0 = *(const float4*)(arow + k0);
  float4 a1 = *(const float4*)(arow + k0 + 4);
  float4 q0 = *(const float4*)(brow + k0);
  float4 q1 = *(const float4*)(brow + k0 + 4);
  float4 c0 = *(const float4*)(b1 + k0);
  float4 c1 = *(const float4*)(b1 + k0 + 4);

  float h0 = fmaxf(a0.x + q0.x + c0.x, 0.f);
  float h1 = fmaxf(a0.y + q0.y + c0.y, 0.f);
  float h2 = fmaxf(a0.z + q0.z + c0.z, 0.f);
  float h3 = fmaxf(a0.w + q0.w + c0.w, 0.f);
  float h4 = fmaxf(a1.x + q1.x + c1.x, 0.f);
  float h5 = fmaxf(a1.y + q1.y + c1.y, 0.f);
  float h6 = fmaxf(a1.z + q1.z + c1.z, 0.f);
  float h7 = fmaxf(a1.w + q1.w + c1.w, 0.f);

  float4 w00 = *(const float4*)(W2 + k0);
  float4 w01 = *(const float4*)(W2 + k0 + 4);
  float4 w10 = *(const float4*)(W2 + 512 + k0);
  float4 w11 = *(const float4*)(W2 + 512 + k0 + 4);

  float acc0 = h0 * w00.x + h1 * w00.y + h2 * w00.z + h3 * w00.w
             + h4 * w01.x + h5 * w01.y + h6 * w01.z + h7 * w01.w;
  float acc1 = h0 * w10.x + h1 * w10.y + h2 * w10.z + h3 * w10.w
             + h4 * w11.x + h5 * w11.y + h6 * w11.z + h7 * w11.w;

  #pragma unroll
  for (int off = 32; off > 0; off >>= 1) {
    acc0 += __shfl_xor(acc0, off, 64);
    acc1 += __shfl_xor(acc1, off, 64);
  }

  if (lane == 0) {
    float s0 = acc0 + b2[0];
    float s1 = acc1 + b2[1];
    const float* u = gu + ((size_t)(b * NPAIR + p)) * 2;
    float g0 = -logf(-logf(u[0] + 1e-10f) + 1e-10f);
    float g1 = -logf(-logf(u[1] + 1e-10f) + 1e-10f);
    int n = n_nodes[b];
    float val = 0.f;
    if (i < n && j < n) val = ((s0 + g0) >= (s1 + g1)) ? 1.f : 0.f;
    adj[(size_t)b * 4096 + i * 64 + j] = val;
    adj[(size_t)b * 4096 + j * 64 + i] = val;
  }
}

// ---------------------------------------------------------------------------
extern "C" void kernel_launch(void* const* d_in, const int* in_sizes, int n_in,
                              void* d_out, int out_size, void* d_ws, size_t ws_size,
                              hipStream_t stream)
{
  (void)in_sizes; (void)n_in; (void)out_size; (void)ws_size;

  const float* z       = (const float*)d_in[0];
  const int*   n_nodes = (const int*)d_in[1];
  const float* gu      = (const float*)d_in[3];
  const float* emb     = (const float*)d_in[4];
  const float* pe      = (const float*)d_in[5];
  const float* W_pre   = (const float*)d_in[6];
  const float* b_pre   = (const float*)d_in[7];
  const float* Wih0    = (const float*)d_in[8];
  const float* Whh0    = (const float*)d_in[9];
  const float* bih0    = (const float*)d_in[10];
  const float* bhh0    = (const float*)d_in[11];
  const float* Wih1    = (const float*)d_in[12];
  const float* Whh1    = (const float*)d_in[13];
  const float* bih1    = (const float*)d_in[14];
  const float* bhh1    = (const float*)d_in[15];
  const float* node_W  = (const float*)d_in[16];
  const float* adj_W1  = (const float*)d_in[17];
  const float* adj_b1  = (const float*)d_in[18];
  const float* adj_W2  = (const float*)d_in[19];
  const float* adj_b2  = (const float*)d_in[20];
  float* adj = (float*)d_out;

  // workspace layout (bytes)
  char* ws = (char*)d_ws;
  float* ZC  = (float*)(ws + 0);         // 192 x 256
  float* ZCW = (float*)(ws + 196608);    // 192 x 1536
  float* WAB = (float*)(ws + 1376256);   // 1024 x 512
  float* H1  = (float*)(ws + 3473408);   // [t][b][512]
  float* H2  = (float*)(ws + 20250624);  // [t][b][512]
  float* GI1 = (float*)(ws + 37027840);  // [t*128+b][1536]
  float* AB  = GI1;                      // aliases GI1 (dead by then)

  // barrier counters in d_out (2 MB, fully rewritten by diag/pair at the end)
  unsigned int* cnt0 = (unsigned int*)d_out;
  unsigned int* cnt1 = cnt0 + 1024;
  hipMemsetAsync(d_out, 0, 8192, stream);

  zc_kernel<<<192, 256, 0, stream>>>(z, pe, emb, W_pre, b_pre, ZC);

  gemm_kernel<false><<<dim3(12, 2), 256, 0, stream>>>(
      ZC, 256, Wih0, 256, nullptr, ZCW, 1536, 192, 1536, 256, nullptr);

  wab_kernel<<<dim3(2, 64, 2), 256, 0, stream>>>(adj_W1, node_W, WAB);

  // GRU layer 0 (persistent cooperative, weights in registers)
  {
    void* args[] = { (void*)&Whh0, (void*)&bhh0, (void*)&H1, (void*)&ZCW,
                     (void*)&bih0, (void*)&n_nodes, (void*)&cnt0 };
    hipLaunchCooperativeKernel((void*)coop_gru_kernel<0>, dim3(256), dim3(512),
                               args, 0, stream);
  }

  // GI1 = H1 @ Wih1^T + bih1
  gemm_kernel<false><<<dim3(12, 64), 256, 0, stream>>>(
      H1, 512, Wih1, 512, bih1, GI1, 1536, 8192, 1536, 512, nullptr);

  // GRU layer 1 (persistent cooperative)
  {
    const float* nil = nullptr;
    void* args[] = { (void*)&Whh1, (void*)&bhh1, (void*)&H2, (void*)&GI1,
                     (void*)&nil, (void*)&nil, (void*)&cnt1 };
    hipLaunchCooperativeKernel((void*)coop_gru_kernel<1>, dim3(256), dim3(512),
                               args, 0, stream);
  }

  // AB = (mask * H2) @ WAB^T
  gemm_kernel<true><<<dim3(8, 64), 256, 0, stream>>>(
      H2, 512, WAB, 512, nullptr, AB, 1024, 8192, 1024, 512, n_nodes);

  diag_kernel<<<32, 256, 0, stream>>>(adj);
  pair_kernel<<<64512, 256, 0, stream>>>(AB, adj_b1, adj_W2, adj_b2, gu, n_nodes, adj);
}

// Round 6
// 3716.952 us; speedup vs baseline: 2.9864x; 2.9864x over previous
//
#include <hip/hip_runtime.h>
#include <math.h>

#define LATENT 256
#define HIDDEN 512
#define MAXN   64
#define BATCH  128
#define NPAIR  2016   // 64*63/2
#define G3     1536   // 3*HIDDEN

// ---------------------------------------------------------------------------
// ZC kernel: rows 0..127 -> Z[b,o] = z[b,:]@W_pre[o,:256]
//            rows 128..191 -> C[m,o] = pe[m,:]@W_pre[o,:256] + emb[m,:]@W_pre[o,256:512] + b_pre[o]
// ---------------------------------------------------------------------------
__global__ __launch_bounds__(256) void zc_kernel(
    const float* __restrict__ z, const float* __restrict__ pe,
    const float* __restrict__ emb, const float* __restrict__ W_pre,
    const float* __restrict__ b_pre, float* __restrict__ ZC)
{
  __shared__ float s1[256];
  __shared__ float s2[256];
  int row = blockIdx.x;     // 0..191
  int o = threadIdx.x;      // 0..255
  const float* wr = W_pre + (size_t)o * 512;
  if (row < 128) {
    s1[o] = z[row * 256 + o];
    __syncthreads();
    float acc = 0.f;
    #pragma unroll 8
    for (int k = 0; k < 256; k += 4) {
      float4 w4 = *(const float4*)(wr + k);
      float4 x4 = *(const float4*)(&s1[k]);
      acc += x4.x * w4.x; acc += x4.y * w4.y; acc += x4.z * w4.z; acc += x4.w * w4.w;
    }
    ZC[row * 256 + o] = acc;
  } else {
    int m = row - 128;
    s1[o] = pe[m * 256 + o];
    s2[o] = emb[m * 256 + o];
    __syncthreads();
    float acc = b_pre[o];
    #pragma unroll 8
    for (int k = 0; k < 256; k += 4) {
      float4 w4 = *(const float4*)(wr + k);
      float4 x4 = *(const float4*)(&s1[k]);
      acc += x4.x * w4.x; acc += x4.y * w4.y; acc += x4.z * w4.z; acc += x4.w * w4.w;
    }
    #pragma unroll 8
    for (int k = 0; k < 256; k += 4) {
      float4 w4 = *(const float4*)(wr + 256 + k);
      float4 x4 = *(const float4*)(&s2[k]);
      acc += x4.x * w4.x; acc += x4.y * w4.y; acc += x4.z * w4.z; acc += x4.w * w4.w;
    }
    ZC[row * 256 + o] = acc;
  }
}

// ---------------------------------------------------------------------------
// Generic f32 GEMM: C[M,N] = A[M,K] @ W[N,K]^T (+bias), optional per-row mask.
// Tiles: 128x128x16, 256 threads, 8x8 micro-tile (split 4+4; pad 137).
// MASK: row m -> t=m>>7, b=m&127 (H layout [t][b]), zero if t >= n_nodes[b].
// ---------------------------------------------------------------------------
template<bool MASK>
__global__ __launch_bounds__(256) void gemm_kernel(
    const float* __restrict__ A, int lda,
    const float* __restrict__ W, int ldw,
    const float* __restrict__ bias,
    float* __restrict__ C, int ldc,
    int M, int N, int K,
    const int* __restrict__ n_nodes)
{
  __shared__ float As[16][137];
  __shared__ float Ws[16][137];
  const int tid = threadIdx.x;
  const int tx = tid & 15, ty = tid >> 4;
  const int row0 = blockIdx.y * 128, col0 = blockIdx.x * 128;

  float acc[8][8];
  #pragma unroll
  for (int i = 0; i < 8; i++)
    #pragma unroll
    for (int j = 0; j < 8; j++) acc[i][j] = 0.f;

  for (int k0 = 0; k0 < K; k0 += 16) {
    #pragma unroll
    for (int s = 0; s < 2; s++) {
      int q = tid + 256 * s;
      int r = q >> 2;
      int c4 = (q & 3) << 2;
      int gm = row0 + r;
      float4 v = make_float4(0.f, 0.f, 0.f, 0.f);
      if (gm < M) {
        v = *(const float4*)(A + (size_t)gm * lda + k0 + c4);
        if (MASK) {
          int tt = gm >> 7, bb = gm & 127;
          if (tt >= n_nodes[bb]) v = make_float4(0.f, 0.f, 0.f, 0.f);
        }
      }
      As[c4 + 0][r] = v.x; As[c4 + 1][r] = v.y; As[c4 + 2][r] = v.z; As[c4 + 3][r] = v.w;
      int gn = col0 + r;
      float4 w = *(const float4*)(W + (size_t)gn * ldw + k0 + c4);
      Ws[c4 + 0][r] = w.x; Ws[c4 + 1][r] = w.y; Ws[c4 + 2][r] = w.z; Ws[c4 + 3][r] = w.w;
    }
    __syncthreads();
    #pragma unroll
    for (int kk = 0; kk < 16; kk++) {
      float4 a0 = *(const float4*)&As[kk][ty * 4];
      float4 a1 = *(const float4*)&As[kk][64 + ty * 4];
      float4 b0 = *(const float4*)&Ws[kk][tx * 4];
      float4 b1 = *(const float4*)&Ws[kk][64 + tx * 4];
      float av[8] = {a0.x, a0.y, a0.z, a0.w, a1.x, a1.y, a1.z, a1.w};
      float bv[8] = {b0.x, b0.y, b0.z, b0.w, b1.x, b1.y, b1.z, b1.w};
      #pragma unroll
      for (int i = 0; i < 8; i++)
        #pragma unroll
        for (int j = 0; j < 8; j++)
          acc[i][j] += av[i] * bv[j];
    }
    __syncthreads();
  }

  float bb[8];
  #pragma unroll
  for (int j = 0; j < 8; j++) {
    int gc = col0 + (j < 4 ? tx * 4 + j : 64 + tx * 4 + j - 4);
    bb[j] = bias ? bias[gc] : 0.f;
  }
  #pragma unroll
  for (int i = 0; i < 8; i++) {
    int gm = row0 + (i < 4 ? ty * 4 + i : 64 + ty * 4 + i - 4);
    if (gm < M) {
      float* out = C + (size_t)gm * ldc + col0;
      float4 o0 = make_float4(acc[i][0] + bb[0], acc[i][1] + bb[1], acc[i][2] + bb[2], acc[i][3] + bb[3]);
      float4 o1 = make_float4(acc[i][4] + bb[4], acc[i][5] + bb[5], acc[i][6] + bb[6], acc[i][7] + bb[7]);
      *(float4*)(out + tx * 4) = o0;
      *(float4*)(out + 64 + tx * 4) = o1;
    }
  }
}

// ---------------------------------------------------------------------------
// WAB precompute: WAB[o,k] (1024x512)
// ---------------------------------------------------------------------------
__global__ __launch_bounds__(256) void wab_kernel(
    const float* __restrict__ adj_W1, const float* __restrict__ node_W,
    float* __restrict__ WAB)
{
  int k = blockIdx.x * 256 + threadIdx.x;  // 0..511
  int o0 = blockIdx.y * 8;
  int sel = blockIdx.z;
  const float* a1 = adj_W1 + (sel ? 512 : 0);
  float acc[8] = {0.f, 0.f, 0.f, 0.f, 0.f, 0.f, 0.f, 0.f};
  for (int j = 0; j < 512; j++) {
    float w = node_W[(size_t)j * 512 + k];
    #pragma unroll
    for (int oo = 0; oo < 8; oo++)
      acc[oo] += a1[(size_t)(o0 + oo) * 1024 + j] * w;
  }
  #pragma unroll
  for (int oo = 0; oo < 8; oo++)
    WAB[(size_t)(sel * 512 + o0 + oo) * 512 + k] = acc[oo];
}

// ---------------------------------------------------------------------------
// Persistent cooperative GRU layer, v3.1: Whh in registers, sized for the
// compiler's 128-VGPR cap (round 4: launch_bounds(512,2) did NOT raise it;
// 96 weight VGPRs spilled -> 8.8 GB/dispatch scratch traffic).
// Grid 256 x 512. group gg = blockIdx&7: 16 batches (b0=gg*16), 32 blocks.
// o-slice r = blockIdx>>3: 16 rows (o0=r*16).
// Thread (ol=tid&15, kq=tid>>4 in 0..31) holds Whh[o0+ol][kq*16..+16) x 3
// gates = 48 weight VGPRs. Batches done in 2 halves of 8 (24 accs reused).
// v3 BUG (round 5 fail): zb preload used `if(tid<768)` with 512 threads ->
// n-gate Z part uninitialized. Restored two-pass loop.
// MODE 0: gi = mask*(Z[b]+C[t]) + bih0 from ZCW; MODE 1: gi = GI1[t*128+b].
// ---------------------------------------------------------------------------
template<int MODE>
__global__ __launch_bounds__(512) void coop_gru_kernel(
    const float* __restrict__ Whh, const float* __restrict__ bhh,
    float* __restrict__ Hbuf, const float* __restrict__ gi,
    const float* __restrict__ bih, const int* __restrict__ n_nodes,
    unsigned int* cnts)
{
  __shared__ float h_s[16 * 512];         // 32 KB: h(t-1) for our 16 batches
  __shared__ float scr[8 * 3 * 16 * 16];  // 24 KB: wave x gate x batch x ol
  __shared__ float zb[3 * 16 * 16];       // 3 KB: MODE0 Z part (t-invariant)
  __shared__ float bhh_s[48];
  __shared__ float bih_s[48];
  __shared__ int   nn_s[16];

  const int tid = threadIdx.x;
  const int ol = tid & 15, kq = tid >> 4;       // kq 0..31
  const int gg = blockIdx.x & 7, r = blockIdx.x >> 3;
  const int b0 = gg * 16, o0 = r * 16;
  unsigned int* cnt = cnts + gg * 64;           // 256B-spaced counters

  // one-time preloads
  if (tid < 48) bhh_s[tid] = bhh[(tid >> 4) * 512 + o0 + (tid & 15)];
  if (MODE == 0) {
    if (tid < 48) bih_s[tid] = bih[(tid >> 4) * 512 + o0 + (tid & 15)];
    if (tid < 16) nn_s[tid] = n_nodes[b0 + tid];
    #pragma unroll
    for (int s = 0; s < 2; s++) {          // 512 threads x 2 passes covers 768
      int q = tid + 512 * s;
      if (q < 768) {
        int g = q >> 8, b = (q >> 4) & 15, o = q & 15;
        zb[q] = gi[(size_t)(b0 + b) * G3 + g * 512 + o0 + o];
      }
    }
  }

  // weights -> registers (held across all 64 steps): 12 float4 = 48 VGPRs
  const float* wb = Whh + (size_t)(o0 + ol) * 512 + kq * 16;
  float4 wr_[4], wz_[4], wn_[4];
  #pragma unroll
  for (int j = 0; j < 4; j++) {
    wr_[j] = *(const float4*)(wb + j * 4);
    wz_[j] = *(const float4*)(wb + 262144 + j * 4);
    wn_[j] = *(const float4*)(wb + 524288 + j * 4);
  }
  __syncthreads();

  const int lane = tid & 63, wl = tid >> 6;

  for (int t = 0; t < 64; t++) {
    // stage h(t-1): 16 batches x 512 = 2048 float4, 4 per thread
    if (t > 0) {
      #pragma unroll
      for (int s = 0; s < 4; s++) {
        int q = tid + 512 * s;
        int rb = q >> 7, c = (q & 127) << 2;
        *(float4*)&h_s[rb * 512 + c] =
            *(const float4*)(Hbuf + ((size_t)((t - 1) * 128 + b0 + rb)) * 512 + c);
      }
    }
    __syncthreads();

    #pragma unroll
    for (int half = 0; half < 2; half++) {
      float accr[8], accz[8], accn[8];
      #pragma unroll
      for (int b = 0; b < 8; b++) { accr[b] = 0.f; accz[b] = 0.f; accn[b] = 0.f; }

      if (t > 0) {
        #pragma unroll
        for (int b = 0; b < 8; b++) {
          const float* hb = &h_s[(half * 8 + b) * 512 + kq * 16];
          #pragma unroll
          for (int j = 0; j < 4; j++) {
            float4 h4 = *(const float4*)(hb + j * 4);
            accr[b] += h4.x * wr_[j].x + h4.y * wr_[j].y + h4.z * wr_[j].z + h4.w * wr_[j].w;
            accz[b] += h4.x * wz_[j].x + h4.y * wz_[j].y + h4.z * wz_[j].z + h4.w * wz_[j].w;
            accn[b] += h4.x * wn_[j].x + h4.y * wn_[j].y + h4.z * wn_[j].z + h4.w * wn_[j].w;
          }
        }
        // fold the 4 kq slices resident in this wave (lane bits 4,5)
        #pragma unroll
        for (int b = 0; b < 8; b++) {
          accr[b] += __shfl_xor(accr[b], 16, 64);
          accz[b] += __shfl_xor(accz[b], 16, 64);
          accn[b] += __shfl_xor(accn[b], 16, 64);
          accr[b] += __shfl_xor(accr[b], 32, 64);
          accz[b] += __shfl_xor(accz[b], 32, 64);
          accn[b] += __shfl_xor(accn[b], 32, 64);
        }
      }

      if (lane < 16) {
        #pragma unroll
        for (int b = 0; b < 8; b++) {
          int bf = half * 8 + b;
          scr[((wl * 3 + 0) * 16 + bf) * 16 + ol] = accr[b];
          scr[((wl * 3 + 1) * 16 + bf) * 16 + ol] = accz[b];
          scr[((wl * 3 + 2) * 16 + bf) * 16 + ol] = accn[b];
        }
      }
    }
    __syncthreads();

    if (tid < 256) {
      int b = tid >> 4, o = tid & 15;
      float sr = 0.f, sz = 0.f, sn = 0.f;
      #pragma unroll
      for (int w = 0; w < 8; w++) {
        sr += scr[((w * 3 + 0) * 16 + b) * 16 + o];
        sz += scr[((w * 3 + 1) * 16 + b) * 16 + o];
        sn += scr[((w * 3 + 2) * 16 + b) * 16 + o];
      }
      float hr = sr + bhh_s[o];
      float hz = sz + bhh_s[16 + o];
      float hn = sn + bhh_s[32 + o];
      float ir, iz, inn;
      if (MODE == 0) {
        bool mk = (t < nn_s[b]);
        const float* ct = gi + (size_t)(128 + t) * G3 + o0 + o;
        float vr = zb[(0 * 16 + b) * 16 + o] + ct[0];
        float vz = zb[(1 * 16 + b) * 16 + o] + ct[512];
        float vn = zb[(2 * 16 + b) * 16 + o] + ct[1024];
        ir  = (mk ? vr : 0.f) + bih_s[o];
        iz  = (mk ? vz : 0.f) + bih_s[16 + o];
        inn = (mk ? vn : 0.f) + bih_s[32 + o];
      } else {
        const float* g1 = gi + (size_t)(t * 128 + b0 + b) * G3 + o0 + o;
        ir = g1[0]; iz = g1[512]; inn = g1[1024];
      }
      float rg = 1.f / (1.f + expf(-(ir + hr)));
      float zg = 1.f / (1.f + expf(-(iz + hz)));
      float ng = tanhf(inn + rg * hn);
      float hp = (t > 0) ? h_s[b * 512 + o0 + o] : 0.f;
      float hnew = (1.f - zg) * ng + zg * hp;
      Hbuf[((size_t)(t * 128 + b0 + b)) * 512 + o0 + o] = hnew;
    }

    if (t < 63) {
      __syncthreads();   // all stores of this block done
      if (tid == 0) {
        __hip_atomic_fetch_add(cnt, 1u, __ATOMIC_RELEASE, __HIP_MEMORY_SCOPE_AGENT);
        unsigned target = 32u * (unsigned)(t + 1);
        while (__hip_atomic_load(cnt, __ATOMIC_RELAXED, __HIP_MEMORY_SCOPE_AGENT) < target)
          __builtin_amdgcn_s_sleep(2);
        (void)__hip_atomic_load(cnt, __ATOMIC_ACQUIRE, __HIP_MEMORY_SCOPE_AGENT);
      }
      __syncthreads();
    }
  }
}

// ---------------------------------------------------------------------------
// Diagonal zero
// ---------------------------------------------------------------------------
__global__ void diag_kernel(float* __restrict__ adj)
{
  int x = blockIdx.x * 256 + threadIdx.x;
  if (x < 8192) {
    int b = x >> 6, d = x & 63;
    adj[(size_t)b * 4096 + d * 65] = 0.f;
  }
}

// ---------------------------------------------------------------------------
// Pair kernel: one wave per (b, pair). AB rows are [t*128+b] layout.
// ---------------------------------------------------------------------------
__global__ __launch_bounds__(256) void pair_kernel(
    const float* __restrict__ AB, const float* __restrict__ b1,
    const float* __restrict__ W2, const float* __restrict__ b2,
    const float* __restrict__ gu, const int* __restrict__ n_nodes,
    float* __restrict__ adj)
{
  int wid = blockIdx.x * 4 + (threadIdx.x >> 6);
  int lane = threadIdx.x & 63;
  int b = wid / NPAIR;
  int p = wid - b * NPAIR;

  float fp = (float)p;
  int i = (int)((127.0f - sqrtf(16129.0f - 8.0f * fp)) * 0.5f);
  if (i < 0) i = 0;
  if (i > 62) i = 62;
  while (i < 62 && (i + 1) * (126 - i) / 2 <= p) i++;
  while (i > 0 && i * (127 - i) / 2 > p) i--;
  int j = p - i * (127 - i) / 2 + i + 1;

  const float* arow = AB + ((size_t)(i * 128 + b)) * 1024;
  const float* brow = AB + ((size_t)(j * 128 + b)) * 1024 + 512;
  int k0 = lane * 8;

  float4 a0 = *(const float4*)(arow + k0);
  float4 a1 = *(const float4*)(arow + k0 + 4);
  float4 q0 = *(const float4*)(brow + k0);
  float4 q1 = *(const float4*)(brow + k0 + 4);
  float4 c0 = *(const float4*)(b1 + k0);
  float4 c1 = *(const float4*)(b1 + k0 + 4);

  float h0 = fmaxf(a0.x + q0.x + c0.x, 0.f);
  float h1 = fmaxf(a0.y + q0.y + c0.y, 0.f);
  float h2 = fmaxf(a0.z + q0.z + c0.z, 0.f);
  float h3 = fmaxf(a0.w + q0.w + c0.w, 0.f);
  float h4 = fmaxf(a1.x + q1.x + c1.x, 0.f);
  float h5 = fmaxf(a1.y + q1.y + c1.y, 0.f);
  float h6 = fmaxf(a1.z + q1.z + c1.z, 0.f);
  float h7 = fmaxf(a1.w + q1.w + c1.w, 0.f);

  float4 w00 = *(const float4*)(W2 + k0);
  float4 w01 = *(const float4*)(W2 + k0 + 4);
  float4 w10 = *(const float4*)(W2 + 512 + k0);
  float4 w11 = *(const float4*)(W2 + 512 + k0 + 4);

  float acc0 = h0 * w00.x + h1 * w00.y + h2 * w00.z + h3 * w00.w
             + h4 * w01.x + h5 * w01.y + h6 * w01.z + h7 * w01.w;
  float acc1 = h0 * w10.x + h1 * w10.y + h2 * w10.z + h3 * w10.w
             + h4 * w11.x + h5 * w11.y + h6 * w11.z + h7 * w11.w;

  #pragma unroll
  for (int off = 32; off > 0; off >>= 1) {
    acc0 += __shfl_xor(acc0, off, 64);
    acc1 += __shfl_xor(acc1, off, 64);
  }

  if (lane == 0) {
    float s0 = acc0 + b2[0];
    float s1 = acc1 + b2[1];
    const float* u = gu + ((size_t)(b * NPAIR + p)) * 2;
    float g0 = -logf(-logf(u[0] + 1e-10f) + 1e-10f);
    float g1 = -logf(-logf(u[1] + 1e-10f) + 1e-10f);
    int n = n_nodes[b];
    float val = 0.f;
    if (i < n && j < n) val = ((s0 + g0) >= (s1 + g1)) ? 1.f : 0.f;
    adj[(size_t)b * 4096 + i * 64 + j] = val;
    adj[(size_t)b * 4096 + j * 64 + i] = val;
  }
}

// ---------------------------------------------------------------------------
extern "C" void kernel_launch(void* const* d_in, const int* in_sizes, int n_in,
                              void* d_out, int out_size, void* d_ws, size_t ws_size,
                              hipStream_t stream)
{
  (void)in_sizes; (void)n_in; (void)out_size; (void)ws_size;

  const float* z       = (const float*)d_in[0];
  const int*   n_nodes = (const int*)d_in[1];
  const float* gu      = (const float*)d_in[3];
  const float* emb     = (const float*)d_in[4];
  const float* pe      = (const float*)d_in[5];
  const float* W_pre   = (const float*)d_in[6];
  const float* b_pre   = (const float*)d_in[7];
  const float* Wih0    = (const float*)d_in[8];
  const float* Whh0    = (const float*)d_in[9];
  const float* bih0    = (const float*)d_in[10];
  const float* bhh0    = (const float*)d_in[11];
  const float* Wih1    = (const float*)d_in[12];
  const float* Whh1    = (const float*)d_in[13];
  const float* bih1    = (const float*)d_in[14];
  const float* bhh1    = (const float*)d_in[15];
  const float* node_W  = (const float*)d_in[16];
  const float* adj_W1  = (const float*)d_in[17];
  const float* adj_b1  = (const float*)d_in[18];
  const float* adj_W2  = (const float*)d_in[19];
  const float* adj_b2  = (const float*)d_in[20];
  float* adj = (float*)d_out;

  // workspace layout (bytes)
  char* ws = (char*)d_ws;
  float* ZC  = (float*)(ws + 0);         // 192 x 256
  float* ZCW = (float*)(ws + 196608);    // 192 x 1536
  float* WAB = (float*)(ws + 1376256);   // 1024 x 512
  float* H1  = (float*)(ws + 3473408);   // [t][b][512]
  float* H2  = (float*)(ws + 20250624);  // [t][b][512]
  float* GI1 = (float*)(ws + 37027840);  // [t*128+b][1536]
  float* AB  = GI1;                      // aliases GI1 (dead by then)

  // barrier counters in d_out (fully rewritten by diag/pair at the end):
  // 8 groups x 64 uints (256 B spacing) per layer
  unsigned int* cnt0 = (unsigned int*)d_out;
  unsigned int* cnt1 = cnt0 + 512;
  hipMemsetAsync(d_out, 0, 4096, stream);

  zc_kernel<<<192, 256, 0, stream>>>(z, pe, emb, W_pre, b_pre, ZC);

  gemm_kernel<false><<<dim3(12, 2), 256, 0, stream>>>(
      ZC, 256, Wih0, 256, nullptr, ZCW, 1536, 192, 1536, 256, nullptr);

  wab_kernel<<<dim3(2, 64, 2), 256, 0, stream>>>(adj_W1, node_W, WAB);

  // GRU layer 0 (persistent cooperative, weights in registers)
  {
    void* args[] = { (void*)&Whh0, (void*)&bhh0, (void*)&H1, (void*)&ZCW,
                     (void*)&bih0, (void*)&n_nodes, (void*)&cnt0 };
    hipLaunchCooperativeKernel((void*)coop_gru_kernel<0>, dim3(256), dim3(512),
                               args, 0, stream);
  }

  // GI1 = H1 @ Wih1^T + bih1
  gemm_kernel<false><<<dim3(12, 64), 256, 0, stream>>>(
      H1, 512, Wih1, 512, bih1, GI1, 1536, 8192, 1536, 512, nullptr);

  // GRU layer 1 (persistent cooperative)
  {
    const float* nil = nullptr;
    void* args[] = { (void*)&Whh1, (void*)&bhh1, (void*)&H2, (void*)&GI1,
                     (void*)&nil, (void*)&nil, (void*)&cnt1 };
    hipLaunchCooperativeKernel((void*)coop_gru_kernel<1>, dim3(256), dim3(512),
                               args, 0, stream);
  }

  // AB = (mask * H2) @ WAB^T
  gemm_kernel<true><<<dim3(8, 64), 256, 0, stream>>>(
      H2, 512, WAB, 512, nullptr, AB, 1024, 8192, 1024, 512, n_nodes);

  diag_kernel<<<32, 256, 0, stream>>>(adj);
  pair_kernel<<<64512, 256, 0, stream>>>(AB, adj_b1, adj_W2, adj_b2, gu, n_nodes, adj);
}